// Round 11
// baseline (209.558 us; speedup 1.0000x reference)
//
#include <hip/hip_runtime.h>
#include <stdint.h>

// Problem constants (fixed by reference)
#define BSZ 2
#define QL 2048
#define KVL 2048
#define NH 16
#define DQK 64
#define DM 1024

typedef __bf16 bf16x8 __attribute__((ext_vector_type(8)));
typedef float f32x4 __attribute__((ext_vector_type(4)));

__device__ __forceinline__ ushort f2bf(float f) {
    union { float f; uint32_t u; } c; c.f = f;
    uint32_t u = c.u;
    return (ushort)((u + 0x7fffu + ((u >> 16) & 1u)) >> 16);
}

// pack two f32 -> two bf16 in one u32 (round-half-up via +0x8000, then v_perm)
__device__ __forceinline__ uint32_t pack2bf(float lo, float hi) {
    union { float f; uint32_t u; } a, b;
    a.f = lo; b.f = hi;
    return __builtin_amdgcn_perm(b.u + 0x8000u, a.u + 0x8000u, 0x07060302u);
}

#define GLOAD_LDS16(g, l)                                              \
    __builtin_amdgcn_global_load_lds(                                  \
        (const __attribute__((address_space(1))) uint32_t*)(g),        \
        (__attribute__((address_space(3))) uint32_t*)(l), 16, 0, 0)

// ---------------- fused prep: rmsnorm (0..4095) + kv cast (4096..8191) + transposes ----------------
__global__ __launch_bounds__(256) void prep_all_k(const float* __restrict__ x,
                                                  const float* __restrict__ w,
                                                  ushort* __restrict__ normed,
                                                  const float* __restrict__ kv_in,
                                                  ushort* __restrict__ kvb,
                                                  const float* __restrict__ w_q,
                                                  const float* __restrict__ w_kv,
                                                  const float* __restrict__ w_o,
                                                  ushort* __restrict__ wqT,
                                                  ushort* __restrict__ wkvT,
                                                  ushort* __restrict__ woT) {
    __shared__ __align__(16) ushort tile[64][65];
    int blk = blockIdx.x;
    int tid = threadIdx.x;
    if (blk < 4096) {
        // RMSNorm row
        float* ws4 = (float*)tile;
        const float4* xr = (const float4*)(x + (size_t)blk * DM);
        float4 v = xr[tid];
        float s = v.x * v.x + v.y * v.y + v.z * v.z + v.w * v.w;
#pragma unroll
        for (int off = 32; off > 0; off >>= 1) s += __shfl_down(s, off, 64);
        if ((tid & 63) == 0) ws4[tid >> 6] = s;
        __syncthreads();
        float tot = ws4[0] + ws4[1] + ws4[2] + ws4[3];
        float r = rsqrtf(tot * (1.0f / DM) + 1e-6f);
        float4 wv = ((const float4*)w)[tid];
        ushort4 o;
        o.x = f2bf(v.x * r * wv.x);
        o.y = f2bf(v.y * r * wv.y);
        o.z = f2bf(v.z * r * wv.z);
        o.w = f2bf(v.w * r * wv.w);
        ((ushort4*)(normed + (size_t)blk * DM))[tid] = o;
        return;
    }
    if (blk < 8192) {
        int i = (blk - 4096) * 256 + tid;  // n4 = 1048576 = 4096*256 exactly
        float4 v = ((const float4*)kv_in)[i];
        ushort4 r;
        r.x = f2bf(v.x); r.y = f2bf(v.y); r.z = f2bf(v.z); r.w = f2bf(v.w);
        ((ushort4*)kvb)[i] = r;
        return;
    }
    int bi = blk - 8192;
    const float* in; ushort* out; int N, bx, by;
    const int K = 1024;
    if (bi < 256)      { in = w_q;  out = wqT;  N = 1024; bx = bi & 15; by = bi >> 4; }
    else if (bi < 768) { int j = bi - 256; in = w_kv; out = wkvT; N = 2048; bx = j & 31; by = j >> 5; }
    else               { int j = bi - 768; in = w_o;  out = woT;  N = 1024; bx = j & 15; by = j >> 4; }
    int k0 = by * 64, n0 = bx * 64;
    int colBase = tid & 63;
    int rowOff = tid >> 6;  // 0..3
#pragma unroll
    for (int i = 0; i < 16; ++i) {
        int row = i * 4 + rowOff;
        tile[colBase][row] = f2bf(in[(size_t)(k0 + row) * N + n0 + colBase]);
    }
    __syncthreads();
#pragma unroll
    for (int i = 0; i < 16; ++i) {
        int nrow = i * 4 + rowOff;
        out[(size_t)(n0 + nrow) * K + k0 + colBase] = tile[nrow][colBase];
    }
}

// ---------------- fused q-proj + kv-proj GEMM, BK=64, swizzled LDS (r10-verified) ----------------
__global__ __launch_bounds__(256) void gemm_qkv_k(
    const ushort* __restrict__ normed, const ushort* __restrict__ kvb,
    const ushort* __restrict__ wqT, const ushort* __restrict__ wkvT,
    ushort* __restrict__ q_out, ushort* __restrict__ k_out, ushort* __restrict__ v_out) {
    __shared__ __align__(16) ushort As[128 * 64];   // 16 KB
    __shared__ __align__(16) ushort Bs[128 * 64];   // 16 KB
    const int K = DM;
    int tid = threadIdx.x;
    int wave = tid >> 6, lane = tid & 63, quad = lane >> 4, l16 = lane & 15;
    int bx = blockIdx.x;
    int isQ = bx < 8;
    const ushort* A = isQ ? normed : kvb;
    const ushort* Bt = isQ ? wqT : wkvT;
    int n0 = (isQ ? bx : bx - 8) * 128;
    int m0 = blockIdx.y * 128;
    int wm = (wave & 1) * 64, wn = (wave >> 1) * 64;

    int r0 = tid >> 3;
    int c0s = (((tid & 7) ^ (r0 & 7)) << 3);
    const ushort* ga0 = &A[(size_t)(m0 + r0) * K + c0s];
    const ushort* gb0 = &Bt[(size_t)(n0 + r0) * K + c0s];
    int xr7 = (l16 & 7) << 4;

    f32x4 zero = {0.f, 0.f, 0.f, 0.f};
    f32x4 acc[4][4];
#pragma unroll
    for (int i = 0; i < 4; ++i)
#pragma unroll
        for (int j = 0; j < 4; ++j) acc[i][j] = zero;

    for (int k0 = 0; k0 < K; k0 += 64) {
#pragma unroll
        for (int p = 0; p < 4; ++p) {
            GLOAD_LDS16(ga0 + (size_t)(p * 32) * K + k0, &As[(tid + p * 256) * 8]);
            GLOAD_LDS16(gb0 + (size_t)(p * 32) * K + k0, &Bs[(tid + p * 256) * 8]);
        }
        __syncthreads();
#pragma unroll
        for (int c = 0; c < 2; ++c) {
            int off = (c * 64 + quad * 16) ^ xr7;   // byte offset within 128B row
            bf16x8 af[4], bfr[4];
#pragma unroll
            for (int mi = 0; mi < 4; ++mi)
                af[mi] = *(const bf16x8*)((const char*)As + (wm + mi * 16 + l16) * 128 + off);
#pragma unroll
            for (int ni = 0; ni < 4; ++ni)
                bfr[ni] = *(const bf16x8*)((const char*)Bs + (wn + ni * 16 + l16) * 128 + off);
#pragma unroll
            for (int mi = 0; mi < 4; ++mi)
#pragma unroll
                for (int ni = 0; ni < 4; ++ni)
                    acc[mi][ni] = __builtin_amdgcn_mfma_f32_16x16x32_bf16(
                        af[mi], bfr[ni], acc[mi][ni], 0, 0, 0);
        }
        __syncthreads();
    }

    const float L2E = 1.44269504089f;
#pragma unroll
    for (int mi = 0; mi < 4; ++mi) {
#pragma unroll
        for (int ni = 0; ni < 4; ++ni) {
#pragma unroll
            for (int r = 0; r < 4; ++r) {
                int mm = m0 + wm + mi * 16 + quad * 4 + r;
                int nn = n0 + wn + ni * 16 + l16;
                float val = acc[mi][ni][r];
                int b = mm >> 11, t = mm & 2047;
                if (isQ) {
                    int h = nn >> 6, d = nn & 63;
                    q_out[((size_t)((b << 4) | h) * QL + t) * DQK + d] = f2bf(val * L2E);
                } else {
                    int c = nn >> 10, h = (nn >> 6) & 15, d = nn & 63;
                    ushort* dst = c ? v_out : k_out;
                    dst[((size_t)((b << 4) | h) * KVL + t) * DQK + d] = f2bf(val);
                }
            }
        }
    }
}

// ---------------- o-projection GEMM, 64x128 tile, BK=64, swizzled LDS + residual (r10) ----------------
__global__ __launch_bounds__(256) void gemm_o_k(const ushort* __restrict__ A,
                                                const ushort* __restrict__ Bt,
                                                const float* __restrict__ resid,
                                                float* __restrict__ f_out) {
    __shared__ __align__(16) ushort As[64 * 64];    // 8 KB
    __shared__ __align__(16) ushort Bs[128 * 64];   // 16 KB
    const int K = DM;
    int tid = threadIdx.x;
    int wave = tid >> 6, lane = tid & 63, quad = lane >> 4, l16 = lane & 15;
    int n0 = blockIdx.x * 128, m0 = blockIdx.y * 64;
    int wm = (wave & 1) * 32, wn = (wave >> 1) * 64;

    int r0 = tid >> 3;
    int c0s = (((tid & 7) ^ (r0 & 7)) << 3);
    const ushort* ga0 = &A[(size_t)(m0 + r0) * K + c0s];
    const ushort* gb0 = &Bt[(size_t)(n0 + r0) * K + c0s];
    int xr7 = (l16 & 7) << 4;

    f32x4 zero = {0.f, 0.f, 0.f, 0.f};
    f32x4 acc[2][4];
#pragma unroll
    for (int i = 0; i < 2; ++i)
#pragma unroll
        for (int j = 0; j < 4; ++j) acc[i][j] = zero;

    for (int k0 = 0; k0 < K; k0 += 64) {
#pragma unroll
        for (int p = 0; p < 2; ++p)
            GLOAD_LDS16(ga0 + (size_t)(p * 32) * K + k0, &As[(tid + p * 256) * 8]);
#pragma unroll
        for (int p = 0; p < 4; ++p)
            GLOAD_LDS16(gb0 + (size_t)(p * 32) * K + k0, &Bs[(tid + p * 256) * 8]);
        __syncthreads();
#pragma unroll
        for (int c = 0; c < 2; ++c) {
            int off = (c * 64 + quad * 16) ^ xr7;
            bf16x8 af[2], bfr[4];
#pragma unroll
            for (int mi = 0; mi < 2; ++mi)
                af[mi] = *(const bf16x8*)((const char*)As + (wm + mi * 16 + l16) * 128 + off);
#pragma unroll
            for (int ni = 0; ni < 4; ++ni)
                bfr[ni] = *(const bf16x8*)((const char*)Bs + (wn + ni * 16 + l16) * 128 + off);
#pragma unroll
            for (int mi = 0; mi < 2; ++mi)
#pragma unroll
                for (int ni = 0; ni < 4; ++ni)
                    acc[mi][ni] = __builtin_amdgcn_mfma_f32_16x16x32_bf16(
                        af[mi], bfr[ni], acc[mi][ni], 0, 0, 0);
        }
        __syncthreads();
    }

#pragma unroll
    for (int mi = 0; mi < 2; ++mi) {
#pragma unroll
        for (int ni = 0; ni < 4; ++ni) {
#pragma unroll
            for (int r = 0; r < 4; ++r) {
                int mm = m0 + wm + mi * 16 + quad * 4 + r;
                int nn = n0 + wn + ni * 16 + l16;
                size_t o = (size_t)mm * DM + nn;
                f_out[o] = resid[o] + acc[mi][ni][r];
            }
        }
    }
}

// ---------------- flash attention with in-staging V transpose ----------------
// grid (QL/128, B*NH), block 256 = 4 waves; wave owns 2 groups of 16 q-columns.
// V is read DIRECTLY from vheads [bh][t][d] (transpose_v kernel deleted): thread
// owns (t-pair 2p, d-chunk); tau preserves t-adjacency (bit0 untouched), so word
// j = {V[2p][d0+j], V[2p+1][d0+j]} (v_perm pair-pack) lands at LDS
// d*128 + (2*tau(2p) ^ ((d&7)<<4)) -- byte-identical to the r9/r10-verified read
// path. Write-side 8-way bank conflicts are timing-hidden (r9: 43x conflict cut = 0us).
// K staging + all reads byte-identical to r10. lsum: r4-proven f32 accumulation.
// No online max: scores*log2e pre-folded in q; exp2 safe in fp32.
__global__ __launch_bounds__(256) void attn_k(const ushort* __restrict__ qh,
                                              const ushort* __restrict__ kh,
                                              const ushort* __restrict__ vh,
                                              ushort* __restrict__ ao) {
    // smem: Ks (64x128B swz) | Vs (64x128B swz, d-major); epilogue reuses as 128x72
    __shared__ __align__(16) ushort smem[128 * 72];  // 18432 B
    char* KsB = (char*)smem;
    char* VsB = (char*)smem + 8192;
    int bh = blockIdx.y, bI = bh >> 4, hI = bh & 15;
    int q0 = blockIdx.x * 128;
    int tid = threadIdx.x, wave = tid >> 6, lane = tid & 63;
    int quad = lane >> 4, l16 = lane & 15;
    const ushort* Qp = qh + (size_t)bh * QL * DQK;
    const ushort* Kp = kh + (size_t)bh * KVL * DQK;
    const ushort* Vp = vh + (size_t)bh * KVL * DQK;   // [t][d]

    // Q fragments (B operand), 2 groups of 16 q-columns per wave
    bf16x8 qf[2][2];
#pragma unroll
    for (int g = 0; g < 2; ++g) {
        const ushort* qrow = Qp + (size_t)(q0 + wave * 32 + g * 16 + l16) * DQK;
        qf[g][0] = *(const bf16x8*)(qrow + quad * 8);
        qf[g][1] = *(const bf16x8*)(qrow + 32 + quad * 8);
    }

    // K staging addressing (r10-identical)
    int srow = tid >> 3;
    int scol = (tid & 7) << 3;
    int stoff = srow * 128 + (((tid & 7) << 4) ^ ((srow & 7) << 4));
    int xr7 = (l16 & 7) << 4;
    int ko0 = (quad * 16) ^ xr7;
    int ko1 = (quad * 16 + 64) ^ xr7;

    // V transpose-staging addressing: thread owns t-pair 2p (p=tid>>3) and d-chunk dc
    int vp2 = (tid >> 3) << 1;            // 2p: 0,2,..,62
    int dc = tid & 7;                     // d0 = dc*8
    // tau(x): bit4->bit2, bit2->bit3, bit3->bit4
    int tau2p = (vp2 & ~28) | ((vp2 & 16) >> 2) | ((vp2 & 4) << 1) | ((vp2 & 8) << 1);
    int vcb = 2 * tau2p;                  // logical byte col of the pair
    char* vwb = VsB + (dc * 8) * 128;     // row d0 base

    f32x4 zero = {0.f, 0.f, 0.f, 0.f};
    f32x4 o[2][4];
#pragma unroll
    for (int g = 0; g < 2; ++g)
#pragma unroll
        for (int i = 0; i < 4; ++i) o[g][i] = zero;
    float lsum[2] = {0.f, 0.f};

    // prefetch tile 0
    uint4 kr0 = *(const uint4*)&Kp[(size_t)srow * DQK + scol];
    uint4 kr1 = *(const uint4*)&Kp[(size_t)(srow + 32) * DQK + scol];
    uint4 va = *(const uint4*)&Vp[(size_t)vp2 * DQK + dc * 8];
    uint4 vb2 = *(const uint4*)&Vp[(size_t)(vp2 + 1) * DQK + dc * 8];

    for (int t0 = 0; t0 < KVL; t0 += 64) {
        *(uint4*)(KsB + stoff) = kr0;
        *(uint4*)(KsB + 4096 + stoff) = kr1;
        {
            uint32_t wv[8];
            wv[0] = __builtin_amdgcn_perm(vb2.x, va.x, 0x05040100u);
            wv[1] = __builtin_amdgcn_perm(vb2.x, va.x, 0x07060302u);
            wv[2] = __builtin_amdgcn_perm(vb2.y, va.y, 0x05040100u);
            wv[3] = __builtin_amdgcn_perm(vb2.y, va.y, 0x07060302u);
            wv[4] = __builtin_amdgcn_perm(vb2.z, va.z, 0x05040100u);
            wv[5] = __builtin_amdgcn_perm(vb2.z, va.z, 0x07060302u);
            wv[6] = __builtin_amdgcn_perm(vb2.w, va.w, 0x05040100u);
            wv[7] = __builtin_amdgcn_perm(vb2.w, va.w, 0x07060302u);
#pragma unroll
            for (int j = 0; j < 8; ++j)
                *(uint32_t*)(vwb + j * 128 + (vcb ^ (j << 4))) = wv[j];
        }
        __syncthreads();
        int tn = t0 + 64;
        if (tn < KVL) {
            kr0 = *(const uint4*)&Kp[(size_t)(tn + srow) * DQK + scol];
            kr1 = *(const uint4*)&Kp[(size_t)(tn + srow + 32) * DQK + scol];
            va = *(const uint4*)&Vp[(size_t)(tn + vp2) * DQK + dc * 8];
            vb2 = *(const uint4*)&Vp[(size_t)(tn + vp2 + 1) * DQK + dc * 8];
        }

        // S^T[t][q] = K·Q^T; K-frag loaded once, used for both q-groups
        f32x4 s[2][4];
#pragma unroll
        for (int mi = 0; mi < 4; ++mi) {
            const char* kb = KsB + (mi * 16 + l16) * 128;
            bf16x8 kf0 = *(const bf16x8*)(kb + ko0);
            bf16x8 kf1 = *(const bf16x8*)(kb + ko1);
#pragma unroll
            for (int g = 0; g < 2; ++g) {
                f32x4 a = zero;
                a = __builtin_amdgcn_mfma_f32_16x16x32_bf16(kf0, qf[g][0], a, 0, 0, 0);
                a = __builtin_amdgcn_mfma_f32_16x16x32_bf16(kf1, qf[g][1], a, 0, 0, 0);
                s[g][mi] = a;
            }
        }

        // softmax numerator: p = exp2(s); pack C-regs straight into PV B-operands.
        bf16x8 pf[2][2];
#pragma unroll
        for (int g = 0; g < 2; ++g) {
            float rs = 0.f;
            uint32_t pw[8];
#pragma unroll
            for (int mi = 0; mi < 4; ++mi) {
                float e0 = __builtin_amdgcn_exp2f(s[g][mi][0]);
                float e1 = __builtin_amdgcn_exp2f(s[g][mi][1]);
                float e2 = __builtin_amdgcn_exp2f(s[g][mi][2]);
                float e3 = __builtin_amdgcn_exp2f(s[g][mi][3]);
                rs += (e0 + e1) + (e2 + e3);
                asm("v_cvt_pk_bf16_f32 %0, %1, %2" : "=v"(pw[mi * 2]) : "v"(e0), "v"(e1));
                asm("v_cvt_pk_bf16_f32 %0, %1, %2" : "=v"(pw[mi * 2 + 1]) : "v"(e2), "v"(e3));
            }
            lsum[g] += rs;
            union { uint32_t u[4]; bf16x8 v; } b0, b1;
            b0.u[0] = pw[0]; b0.u[1] = pw[1]; b0.u[2] = pw[2]; b0.u[3] = pw[3];
            b1.u[0] = pw[4]; b1.u[1] = pw[5]; b1.u[2] = pw[6]; b1.u[3] = pw[7];
            pf[g][0] = b0.v;
            pf[g][1] = b1.v;
        }

        // O^T += V^T · P^T; V-frag loaded once, used for both q-groups
#pragma unroll
        for (int mi = 0; mi < 4; ++mi) {
            const char* vb = VsB + (mi * 16 + l16) * 128;
            bf16x8 vf0 = *(const bf16x8*)(vb + ko0);
            bf16x8 vf1 = *(const bf16x8*)(vb + ko1);
#pragma unroll
            for (int g = 0; g < 2; ++g) {
                o[g][mi] = __builtin_amdgcn_mfma_f32_16x16x32_bf16(vf0, pf[g][0], o[g][mi], 0, 0, 0);
                o[g][mi] = __builtin_amdgcn_mfma_f32_16x16x32_bf16(vf1, pf[g][1], o[g][mi], 0, 0, 0);
            }
        }
        __syncthreads();
    }

    // epilogue: reduce l across quads, O^T -> O via LDS (128x72 transpose buffer)
#pragma unroll
    for (int g = 0; g < 2; ++g) {
        float lg = lsum[g];
        lg += __shfl_xor(lg, 16, 64);
        lg += __shfl_xor(lg, 32, 64);
        float rinv = __builtin_amdgcn_rcpf(lg);
        ushort* orow = &smem[(size_t)(wave * 32 + g * 16 + l16) * 72];
#pragma unroll
        for (int mi = 0; mi < 4; ++mi) {
            uint2 pk;
            pk.x = pack2bf(o[g][mi][0] * rinv, o[g][mi][1] * rinv);
            pk.y = pack2bf(o[g][mi][2] * rinv, o[g][mi][3] * rinv);
            *(uint2*)&orow[mi * 16 + quad * 4] = pk;
        }
    }
    __syncthreads();
#pragma unroll
    for (int it = 0; it < 4; ++it) {
        int idx = tid + it * 256;
        int ql = idx >> 3, c = (idx & 7) << 3;
        uint4 vv = *(const uint4*)&smem[ql * 72 + c];
        *(uint4*)&ao[((size_t)(bI * QL + q0 + ql)) * DM + hI * 64 + c] = vv;
    }
}

extern "C" void kernel_launch(void* const* d_in, const int* in_sizes, int n_in,
                              void* d_out, int out_size, void* d_ws, size_t ws_size,
                              hipStream_t stream) {
    (void)in_sizes; (void)n_in; (void)out_size; (void)ws_size;
    const float* qh_in = (const float*)d_in[0];
    const float* kv_in = (const float*)d_in[2];
    const float* w_q  = (const float*)d_in[4];
    const float* w_kv = (const float*)d_in[5];
    const float* w_o  = (const float*)d_in[6];
    const float* lnw  = (const float*)d_in[7];
    float* out = (float*)d_out;

    char* ws = (char*)d_ws;
    ushort* normed = (ushort*)(ws);                        // 8 MB
    ushort* kvb    = (ushort*)(ws + ((size_t)8 << 20));    // 8 MB
    ushort* wqT    = (ushort*)(ws + ((size_t)16 << 20));   // 2 MB
    ushort* wkvT   = (ushort*)(ws + ((size_t)18 << 20));   // 4 MB
    ushort* woT    = (ushort*)(ws + ((size_t)22 << 20));   // 2 MB
    ushort* qheads = (ushort*)(ws + ((size_t)24 << 20));   // 8 MB  [bh][q][d] (pre-scaled by log2e)
    ushort* kheads = (ushort*)(ws + ((size_t)32 << 20));   // 8 MB  [bh][t][d]
    ushort* vheads = (ushort*)(ws + ((size_t)40 << 20));   // 8 MB  [bh][t][d]
    ushort* attno  = (ushort*)(ws + ((size_t)48 << 20));   // 8 MB  [b*q][1024]

    prep_all_k<<<4096 + 4096 + 1024, 256, 0, stream>>>(qh_in, lnw, normed, kv_in, kvb,
                                                       w_q, w_kv, w_o, wqT, wkvT, woT);
    gemm_qkv_k<<<dim3(24, 32), 256, 0, stream>>>(normed, kvb, wqT, wkvT,
                                                 qheads, kheads, vheads);
    attn_k<<<dim3(QL / 128, BSZ * NH), 256, 0, stream>>>(qheads, kheads, vheads, attno);
    gemm_o_k<<<dim3(8, 64), 256, 0, stream>>>(attno, woT, qh_in, out);
}